// Round 13
// baseline (686.030 us; speedup 1.0000x reference)
//
#include <hip/hip_runtime.h>
#include <math.h>

// SpikingSelfAttention: B=8 S=1024 E=768 H=12 D=64 T=10
constexpr int B_ = 8, S_ = 1024, E_ = 768, H_ = 12, D_ = 64, T_ = 10;
constexpr int N_ = B_ * S_;        // 8192
constexpr int NE_ = N_ * E_;       // 6291456
constexpr int WE_ = E_ * E_;       // 589824

typedef __attribute__((ext_vector_type(8))) short bf16x8;
typedef __attribute__((ext_vector_type(4))) float f32x4;

#define MFMA16(a,b,c) __builtin_amdgcn_mfma_f32_16x16x32_bf16(a,b,c,0,0,0)

__device__ __forceinline__ float sigm(float z){ return 1.f/(1.f+__expf(-z)); }
__device__ __forceinline__ unsigned short f2bf(float f){
    unsigned int u = __float_as_uint(f);
    u += 0x7FFFu + ((u>>16)&1u);           // RN-even
    return (unsigned short)(u>>16);
}
__device__ __forceinline__ float bf2f(unsigned short h){
    return __uint_as_float(((unsigned int)h)<<16);
}
__device__ __forceinline__ void gl16(const void* g, void* l){
    __builtin_amdgcn_global_load_lds((const __attribute__((address_space(1))) unsigned int*)g,
                                     (__attribute__((address_space(3))) unsigned int*)l, 16, 0, 0);
}

// ---------------------------------------------------------------------------
// encode: enc[t][n][e] = bf16(sigmoid(100*clip(x,0,1) - 10t)), 8 elems/thread
__global__ __launch_bounds__(256) void encode_k(const float* __restrict__ x,
                                                unsigned short* __restrict__ enc){
    const int i = blockIdx.x*256 + threadIdx.x;
    const float4 a = ((const float4*)x)[2*i];
    const float4 b = ((const float4*)x)[2*i+1];
    float p[8] = {a.x,a.y,a.z,a.w,b.x,b.y,b.z,b.w};
#pragma unroll
    for (int e=0;e<8;++e) p[e] = 100.f*fminf(fmaxf(p[e],0.f),1.f);
#pragma unroll
    for (int t=0;t<T_;++t){
        unsigned int w[4];
#pragma unroll
        for (int e=0;e<4;++e){
            unsigned short u0 = f2bf(sigm(p[2*e]   - 10.f*(float)t));
            unsigned short u1 = f2bf(sigm(p[2*e+1] - 10.f*(float)t));
            w[e] = (unsigned int)u0 | ((unsigned int)u1<<16);
        }
        ((uint4*)(enc + (long)t*NE_))[i] = make_uint4(w[0],w[1],w[2],w[3]);
    }
}

// ---------------------------------------------------------------------------
// split weights into hi/lo bf16: whi[z], wlo[z], z in {q,k,v,o}
__global__ __launch_bounds__(256) void wsplit_k(const float* __restrict__ Wq, const float* __restrict__ Wk,
        const float* __restrict__ Wv, const float* __restrict__ Wo,
        unsigned short* __restrict__ whi, unsigned short* __restrict__ wlo){
    int gi = blockIdx.x*256 + threadIdx.x;
    int z = gi / (WE_/8);
    int r = gi % (WE_/8);
    const float* W = z==0?Wq : z==1?Wk : z==2?Wv : Wo;
    const float4 a = ((const float4*)W)[2*r];
    const float4 b = ((const float4*)W)[2*r+1];
    float f[8]={a.x,a.y,a.z,a.w,b.x,b.y,b.z,b.w};
    unsigned int h[4], l[4];
#pragma unroll
    for (int e=0;e<4;++e){
        unsigned short h0=f2bf(f[2*e]),   l0=f2bf(f[2*e]  -bf2f(h0));
        unsigned short h1=f2bf(f[2*e+1]), l1=f2bf(f[2*e+1]-bf2f(h1));
        h[e] = (unsigned)h0 | ((unsigned)h1<<16);
        l[e] = (unsigned)l0 | ((unsigned)l1<<16);
    }
    ((uint4*)(whi + (long)z*WE_))[r] = make_uint4(h[0],h[1],h[2],h[3]);
    ((uint4*)(wlo + (long)z*WE_))[r] = make_uint4(l[0],l[1],l[2],l[3]);
}

// ---------------------------------------------------------------------------
// fused QKV GEMM (MFMA, W plain bf16) + in-register LIF over 10 timesteps.
// BEST MEASURED CONFIG (r9/r12, 415us): tile 128x64, 4 waves (2x2),
// single-buffered 24KB LDS, plain __syncthreads, natural grid dim3(64,12,3).
// NEW: epilogue writes hi/lo-split bf16 (and V transposed per-head) so
// attn_k2 can stage via pure global_load_lds with no per-tile f2bf VALU.
__global__ __launch_bounds__(256,2) void qkv_k(const unsigned short* __restrict__ enc,
        const unsigned short* __restrict__ whi,
        const float* __restrict__ bq, const float* __restrict__ bk, const float* __restrict__ bv,
        unsigned short* __restrict__ Qh_g, unsigned short* __restrict__ Ql_g,
        unsigned short* __restrict__ Kh_g, unsigned short* __restrict__ Kl_g,
        unsigned short* __restrict__ Vth_g, unsigned short* __restrict__ Vtl_g){
    const int z = blockIdx.z;
    const unsigned short* Wh = whi + (long)z*WE_;
    const float* bias = z==0?bq : z==1?bk : bv;
    const int row0 = blockIdx.x*128, col0 = blockIdx.y*64;

    __shared__ unsigned short Ab[128*64];   // 16KB
    __shared__ unsigned short Bh[64*64];    // 8KB

    const int tid = threadIdx.x, lane = tid&63, wid = tid>>6;
    const int l15 = lane&15, l4 = lane>>4, l7 = lane&7;
    const int wr = wid>>1, wc = wid&1;

    // staging source offsets (element units); LDS dest linear, source pre-inverse-swizzled
    int aSrc[4], bSrc[2];
#pragma unroll
    for (int s=0;s<4;++s){
        int idx = (wid + s*4)*64 + lane;      // [0,1024)
        int row = idx>>3, ch = idx&7;
        aSrc[s] = (row0+row)*E_ + ((ch ^ (row&7))<<3);
    }
#pragma unroll
    for (int s=0;s<2;++s){
        int idx = (wid + s*4)*64 + lane;      // [0,512)
        int row = idx>>3, ch = idx&7;
        bSrc[s] = (col0+row)*E_ + ((ch ^ (row&7))<<3);
    }

    const int aBase = (wr*64 + l15)*128;
    const int bBase = (wc*32 + l15)*128;
    const int sw[2] = { ((l4^l7)<<4), ((((4+l4))^l7)<<4) };

    f32x4 acc[4][2];
    float vm[4][2][4] = {};     // membrane potential (registers across t)
    float qa[4][2][4] = {};     // spike accumulator
    float bn[2];
#pragma unroll
    for (int n=0;n<2;++n) bn[n] = bias[col0 + wc*32 + n*16 + l15];
    const f32x4 zero4 = {0.f,0.f,0.f,0.f};

    for (int t=0;t<T_;++t){
        const long tb = (long)t*NE_;
#pragma unroll
        for (int m=0;m<4;++m)
#pragma unroll
            for (int n=0;n<2;++n) acc[m][n] = zero4;
        for (int kt=0;kt<12;++kt){
            const int k0 = kt*64;
            __syncthreads();
#pragma unroll
            for (int s=0;s<4;++s)
                gl16(enc + tb + aSrc[s] + k0, &Ab[(wid+s*4)*512]);
#pragma unroll
            for (int s=0;s<2;++s)
                gl16(Wh + bSrc[s] + k0, &Bh[(wid+s*4)*512]);
            __syncthreads();
#pragma unroll
            for (int kk=0;kk<2;++kk){
                bf16x8 af[4], fbh[2];
#pragma unroll
                for (int m=0;m<4;++m)
                    af[m] = *(const bf16x8*)((const char*)Ab + aBase + m*2048 + sw[kk]);
#pragma unroll
                for (int n=0;n<2;++n)
                    fbh[n] = *(const bf16x8*)((const char*)Bh + bBase + n*2048 + sw[kk]);
#pragma unroll
                for (int m=0;m<4;++m)
#pragma unroll
                    for (int n=0;n<2;++n)
                        acc[m][n] = MFMA16(af[m], fbh[n], acc[m][n]);
            }
        }
        // LIF update, registers only (no barrier needed)
#pragma unroll
        for (int m=0;m<4;++m)
#pragma unroll
            for (int n=0;n<2;++n)
#pragma unroll
                for (int j=0;j<4;++j){
                    float I = acc[m][n][j] + bn[n];
                    float v = (vm[m][n][j] + I)*0.5f;
                    float s = sigm(10.f*v - 10.f);
                    vm[m][n][j] = v*(1.f - s);
                    qa[m][n][j] += s;
                }
    }
    // epilogue: write hi/lo split bf16
    if (z == 2){
        // V transposed per head: Vt[(b*12+h)*64 + d][key], 4 keys packed per 8B
        const int b = blockIdx.x >> 3;
        const long vtb = (long)(b*12 + blockIdx.y) * 65536;   // *64*1024
        const int keyb = (blockIdx.x & 7)*128 + wr*64 + l4*4;
#pragma unroll
        for (int m=0;m<4;++m)
#pragma unroll
            for (int n=0;n<2;++n){
                const int d = wc*32 + n*16 + l15;
                unsigned int hw[2], lw[2];
#pragma unroll
                for (int jp=0;jp<2;++jp){
                    float v0 = qa[m][n][jp*2], v1 = qa[m][n][jp*2+1];
                    unsigned short h0=f2bf(v0), h1=f2bf(v1);
                    unsigned short l0=f2bf(v0-bf2f(h0)), l1=f2bf(v1-bf2f(h1));
                    hw[jp] = (unsigned)h0 | ((unsigned)h1<<16);
                    lw[jp] = (unsigned)l0 | ((unsigned)l1<<16);
                }
                long o = vtb + (long)d*1024 + keyb + m*16;
                *(uint2*)&Vth_g[o] = make_uint2(hw[0],hw[1]);
                *(uint2*)&Vtl_g[o] = make_uint2(lw[0],lw[1]);
            }
    } else {
        unsigned short* Oh = (z==0) ? Qh_g : Kh_g;
        unsigned short* Ol = (z==0) ? Ql_g : Kl_g;
#pragma unroll
        for (int m=0;m<4;++m)
#pragma unroll
            for (int n=0;n<2;++n)
#pragma unroll
                for (int j=0;j<4;++j){
                    int row = row0 + wr*64 + m*16 + l4*4 + j;
                    int col = col0 + wc*32 + n*16 + l15;
                    float v = qa[m][n][j];
                    unsigned short hh = f2bf(v);
                    unsigned short ll = f2bf(v - bf2f(hh));
                    Oh[(long)row*E_ + col] = hh;
                    Ol[(long)row*E_ + col] = ll;
                }
    }
}

// ---------------------------------------------------------------------------
// flash attention, hi/lo-split bf16 MFMA. Per block: 64 q-rows, one (b,h).
// All staging is now pure global_load_lds (inputs pre-split/pre-transposed
// by qkv_k; source pre-inverse-swizzled, LDS contents bit-identical to r12).
__global__ __launch_bounds__(256,2) void attn_k2(
        const unsigned short* __restrict__ Qh_g, const unsigned short* __restrict__ Ql_g,
        const unsigned short* __restrict__ Kh_g, const unsigned short* __restrict__ Kl_g,
        const unsigned short* __restrict__ Vth_g, const unsigned short* __restrict__ Vtl_g,
        unsigned short* __restrict__ atth, unsigned short* __restrict__ attl){
    const int q0 = blockIdx.x*64;
    const int h  = blockIdx.y;
    const int b  = blockIdx.z;
    const long base = ((long)b*S_)*E_ + h*64;
    const long vtb  = (long)(b*12 + h) * 65536;

    __shared__ char smem[65536];
    unsigned short* QhL = (unsigned short*)(smem);
    unsigned short* QlL = (unsigned short*)(smem + 8192);
    unsigned short* KhL = (unsigned short*)(smem + 16384);
    unsigned short* KlL = (unsigned short*)(smem + 24576);
    unsigned short* VhL = (unsigned short*)(smem + 32768);  // [d][key] transposed
    unsigned short* VlL = (unsigned short*)(smem + 40960);
    unsigned short* Ph = (unsigned short*)(smem + 49152);   // [q][key]
    unsigned short* Pl = (unsigned short*)(smem + 57344);
    float* OT = (float*)(smem + 16384);                     // [64][68] reuse K/V region

    const int tid = threadIdx.x, lane = tid&63, wid = tid>>6;
    const int l15 = lane&15, l4 = lane>>4, l7 = lane&7;
    const int qrow = wid*16 + l15;

    // staging source offsets (element units), LDS dest linear
    int sOff[2], vOff[2];
#pragma unroll
    for (int s=0;s<2;++s){
        int idx = (wid + s*4)*64 + lane;      // [0,512)
        int r = idx>>3, c = idx&7;
        sOff[s] = r*E_ + ((c ^ (r&7))<<3);    // Q/K rows in [N][E]
        vOff[s] = (r<<10) + ((c ^ (r&7))<<3); // Vt rows (d) stride 1024
    }

    // stage Q (hi+lo) once
#pragma unroll
    for (int s=0;s<2;++s){
        gl16(Qh_g + base + (long)q0*E_ + sOff[s], &QhL[(wid+s*4)*512]);
        gl16(Ql_g + base + (long)q0*E_ + sOff[s], &QlL[(wid+s*4)*512]);
    }
    __syncthreads();
    bf16x8 qfh[2], qfl[2];
#pragma unroll
    for (int kk=0;kk<2;++kk){
        int off = qrow*128 + ((((kk<<2)+l4) ^ l7)<<4);
        qfh[kk] = *(const bf16x8*)((const char*)QhL + off);
        qfl[kk] = *(const bf16x8*)((const char*)QlL + off);
    }

    float mrun = -1e30f, lrun = 0.f;
    f32x4 ot[4];
    const f32x4 zero4 = {0.f,0.f,0.f,0.f};
#pragma unroll
    for (int m=0;m<4;++m) ot[m] = zero4;

    for (int kt=0;kt<16;++kt){
        const int k0 = kt*64;
        __syncthreads();   // previous tile's LDS reads done
#pragma unroll
        for (int s=0;s<2;++s){
            gl16(Kh_g + base + (long)k0*E_ + sOff[s], &KhL[(wid+s*4)*512]);
            gl16(Kl_g + base + (long)k0*E_ + sOff[s], &KlL[(wid+s*4)*512]);
            gl16(Vth_g + vtb + k0 + vOff[s], &VhL[(wid+s*4)*512]);
            gl16(Vtl_g + vtb + k0 + vOff[s], &VlL[(wid+s*4)*512]);
        }
        __syncthreads();
        // S^T = K * Q^T  (3 hi/lo products)
        f32x4 st[4];
#pragma unroll
        for (int m=0;m<4;++m) st[m] = zero4;
#pragma unroll
        for (int kk=0;kk<2;++kk){
            int swo = ((((kk<<2)+l4) ^ l7)<<4);
            bf16x8 kh[4], kl2[4];
#pragma unroll
            for (int m=0;m<4;++m){
                int off = (m*16+l15)*128 + swo;
                kh[m]  = *(const bf16x8*)((const char*)KhL + off);
                kl2[m] = *(const bf16x8*)((const char*)KlL + off);
            }
#pragma unroll
            for (int m=0;m<4;++m){
                st[m] = MFMA16(kh[m],  qfh[kk], st[m]);
                st[m] = MFMA16(kh[m],  qfl[kk], st[m]);
                st[m] = MFMA16(kl2[m], qfh[kk], st[m]);
            }
        }
        // online softmax (lane's q = qrow; 4 lanes share a q via xor16/32)
        float pmax = -1e30f;
#pragma unroll
        for (int m=0;m<4;++m)
#pragma unroll
            for (int j=0;j<4;++j){ st[m][j] *= 0.125f; pmax = fmaxf(pmax, st[m][j]); }
        pmax = fmaxf(pmax, __shfl_xor(pmax,16));
        pmax = fmaxf(pmax, __shfl_xor(pmax,32));
        float mnew = fmaxf(mrun, pmax);
        float alpha = __expf(mrun - mnew);
        float p[16]; float psum = 0.f;
#pragma unroll
        for (int m=0;m<4;++m)
#pragma unroll
            for (int j=0;j<4;++j){ float e = __expf(st[m][j]-mnew); p[m*4+j]=e; psum+=e; }
        psum += __shfl_xor(psum,16);
        psum += __shfl_xor(psum,32);
        lrun = lrun*alpha + psum;
        mrun = mnew;
#pragma unroll
        for (int m=0;m<4;++m)
#pragma unroll
            for (int j=0;j<4;++j) ot[m][j] *= alpha;
        // write P^T split (wave-private rows, packed pairs)
#pragma unroll
        for (int m=0;m<4;++m)
#pragma unroll
            for (int jp=0;jp<2;++jp){
                float fx = p[m*4+jp*2], fy = p[m*4+jp*2+1];
                unsigned short hx=f2bf(fx), hy=f2bf(fy);
                unsigned short lx=f2bf(fx-bf2f(hx)), ly=f2bf(fy-bf2f(hy));
                int key = m*16 + l4*4 + jp*2;
                int byte = qrow*128 + ((key<<1) ^ (l7<<4));
                *(unsigned int*)((char*)Ph + byte) = (unsigned)hx | ((unsigned)hy<<16);
                *(unsigned int*)((char*)Pl + byte) = (unsigned)lx | ((unsigned)ly<<16);
            }
        // O^T += V^T * P^T (3 hi/lo products)
#pragma unroll
        for (int kk=0;kk<2;++kk){
            int swo = ((((kk<<2)+l4) ^ l7)<<4);
            bf16x8 pfh = *(const bf16x8*)((const char*)Ph + qrow*128 + swo);
            bf16x8 pfl = *(const bf16x8*)((const char*)Pl + qrow*128 + swo);
#pragma unroll
            for (int m=0;m<4;++m){
                int off = (m*16+l15)*128 + swo;
                bf16x8 vvh = *(const bf16x8*)((const char*)VhL + off);
                bf16x8 vvl = *(const bf16x8*)((const char*)VlL + off);
                ot[m] = MFMA16(vvh, pfh, ot[m]);
                ot[m] = MFMA16(vvh, pfl, ot[m]);
                ot[m] = MFMA16(vvl, pfh, ot[m]);
            }
        }
    }
    __syncthreads();
    // normalize + transpose via LDS, write att split bf16
    float inv = 1.f/lrun;
#pragma unroll
    for (int m=0;m<4;++m)
#pragma unroll
        for (int j=0;j<4;++j){
            int d = m*16 + l4*4 + j;
            OT[qrow*68 + d] = ot[m][j]*inv;
        }
    __syncthreads();
    {
        int q = tid>>2, d0 = (tid&3)*16;
        const float* rp = OT + q*68 + d0;
        float4 f0=((const float4*)rp)[0], f1=((const float4*)rp)[1];
        float4 f2=((const float4*)rp)[2], f3=((const float4*)rp)[3];
        float f[16]={f0.x,f0.y,f0.z,f0.w,f1.x,f1.y,f1.z,f1.w,f2.x,f2.y,f2.z,f2.w,f3.x,f3.y,f3.z,f3.w};
        bf16x8 vh[2], vl[2];
#pragma unroll
        for (int g=0;g<2;++g)
#pragma unroll
            for (int e=0;e<8;++e){
                unsigned short hh = f2bf(f[g*8+e]);
                vh[g][e] = (short)hh;
                vl[g][e] = (short)f2bf(f[g*8+e]-bf2f(hh));
            }
        long o = base + (long)(q0+q)*E_ + d0;
        *(bf16x8*)(atth + o)     = vh[0];
        *(bf16x8*)(atth + o + 8) = vh[1];
        *(bf16x8*)(attl + o)     = vl[0];
        *(bf16x8*)(attl + o + 8) = vl[1];
    }
}

// ---------------------------------------------------------------------------
// output projection GEMM: (att_hi + att_lo) x Wo_hi (2 products) + spike
__global__ __launch_bounds__(256,2) void out_k(const unsigned short* __restrict__ Ah_g,
        const unsigned short* __restrict__ Al_g,
        const unsigned short* __restrict__ Wh,
        const float* __restrict__ bias, float* __restrict__ out){
    const int row0 = blockIdx.x*128, col0 = blockIdx.y*64;
    __shared__ unsigned short Ah[128*64], Al[128*64];
    __shared__ unsigned short Bh2[64*64];

    const int tid = threadIdx.x, lane = tid&63, wid = tid>>6;
    const int l15 = lane&15, l4 = lane>>4, l7 = lane&7;
    const int wr = wid>>1, wc = wid&1;

    int aSrc[4], bSrc[2];
#pragma unroll
    for (int s=0;s<4;++s){
        int idx = (wid + s*4)*64 + lane;
        int row = idx>>3, ch = idx&7;
        aSrc[s] = (row0+row)*E_ + ((ch ^ (row&7))<<3);
    }
#pragma unroll
    for (int s=0;s<2;++s){
        int idx = (wid + s*4)*64 + lane;
        int row = idx>>3, ch = idx&7;
        bSrc[s] = (col0+row)*E_ + ((ch ^ (row&7))<<3);
    }
    const int aBase = (wr*64 + l15)*128;
    const int bBase = (wc*32 + l15)*128;
    const int sw[2] = { ((l4^l7)<<4), ((((4+l4))^l7)<<4) };

    f32x4 acc[4][2];
    const f32x4 zero4 = {0.f,0.f,0.f,0.f};
#pragma unroll
    for (int m=0;m<4;++m)
#pragma unroll
        for (int n=0;n<2;++n) acc[m][n] = zero4;

    for (int kt=0;kt<12;++kt){
        const int k0 = kt*64;
        __syncthreads();
#pragma unroll
        for (int s=0;s<4;++s){
            gl16(Ah_g + aSrc[s] + k0, &Ah[(wid+s*4)*512]);
            gl16(Al_g + aSrc[s] + k0, &Al[(wid+s*4)*512]);
        }
#pragma unroll
        for (int s=0;s<2;++s)
            gl16(Wh + bSrc[s] + k0, &Bh2[(wid+s*4)*512]);
        __syncthreads();
#pragma unroll
        for (int kk=0;kk<2;++kk){
            bf16x8 ah[4], al[4], fbh[2];
#pragma unroll
            for (int m=0;m<4;++m){
                ah[m] = *(const bf16x8*)((const char*)Ah + aBase + m*2048 + sw[kk]);
                al[m] = *(const bf16x8*)((const char*)Al + aBase + m*2048 + sw[kk]);
            }
#pragma unroll
            for (int n=0;n<2;++n)
                fbh[n] = *(const bf16x8*)((const char*)Bh2 + bBase + n*2048 + sw[kk]);
#pragma unroll
            for (int m=0;m<4;++m)
#pragma unroll
                for (int n=0;n<2;++n){
                    acc[m][n] = MFMA16(ah[m], fbh[n], acc[m][n]);
                    acc[m][n] = MFMA16(al[m], fbh[n], acc[m][n]);
                }
        }
    }
#pragma unroll
    for (int m=0;m<4;++m)
#pragma unroll
        for (int n=0;n<2;++n){
            float bn = bias[col0 + wc*32 + n*16 + l15];
#pragma unroll
            for (int j=0;j<4;++j){
                int row = row0 + wr*64 + m*16 + l4*4 + j;
                int col = col0 + wc*32 + n*16 + l15;
                float I = acc[m][n][j] + bn;
                out[(long)row*E_ + col] = sigm(5.f*I - 10.f);   // lif_step(0, I) spike
            }
        }
}

// ---------------------------------------------------------------------------
extern "C" void kernel_launch(void* const* d_in, const int* in_sizes, int n_in,
                              void* d_out, int out_size, void* d_ws, size_t ws_size,
                              hipStream_t stream){
    const float* x  = (const float*)d_in[0];
    const float* Wq = (const float*)d_in[1];
    const float* bq = (const float*)d_in[2];
    const float* Wk = (const float*)d_in[3];
    const float* bk = (const float*)d_in[4];
    const float* Wv = (const float*)d_in[5];
    const float* bv = (const float*)d_in[6];
    const float* Wo = (const float*)d_in[7];
    const float* bo = (const float*)d_in[8];
    float* out = (float*)d_out;

    // ws layout (210763776 B total, same as before):
    //  [0, 125829120)            enc bf16 [10][N][E]   (dead after qkv_k; att reuses)
    //  [125829120, 135266304)    whi/wlo bf16 [4][E*E]
    //  [135266304, 210763776)    Qh/Ql/Kh/Kl [N][E] bf16 + Vth/Vtl [B*H*64][S] bf16
    char* ws = (char*)d_ws;
    unsigned short* enc  = (unsigned short*)ws;
    unsigned short* atth = (unsigned short*)ws;
    unsigned short* attl = (unsigned short*)(ws + (long)NE_*2);
    unsigned short* whi  = (unsigned short*)(ws + 125829120L);
    unsigned short* wlo  = whi + 4L*WE_;
    unsigned short* Qh_g  = (unsigned short*)(ws + 135266304L);
    unsigned short* Ql_g  = Qh_g + NE_;
    unsigned short* Kh_g  = Ql_g + NE_;
    unsigned short* Kl_g  = Kh_g + NE_;
    unsigned short* Vth_g = Kl_g + NE_;
    unsigned short* Vtl_g = Vth_g + NE_;

    wsplit_k<<<dim3(4*(WE_/8)/256), 256, 0, stream>>>(Wq,Wk,Wv,Wo,whi,wlo);
    encode_k<<<dim3(NE_/8/256), 256, 0, stream>>>(x,enc);
    qkv_k<<<dim3(64,12,3), 256, 0, stream>>>(enc,whi,bq,bk,bv,
                                             Qh_g,Ql_g,Kh_g,Kl_g,Vth_g,Vtl_g);
    attn_k2<<<dim3(16,12,8), 256, 0, stream>>>(Qh_g,Ql_g,Kh_g,Kl_g,Vth_g,Vtl_g,
                                               atth,attl);
    out_k<<<dim3(64,12), 256, 0, stream>>>(atth,attl,whi+3L*WE_,bo,out);
}

// Round 14
// 584.057 us; speedup vs baseline: 1.1746x; 1.1746x over previous
//
#include <hip/hip_runtime.h>
#include <math.h>

// SpikingSelfAttention: B=8 S=1024 E=768 H=12 D=64 T=10
constexpr int B_ = 8, S_ = 1024, E_ = 768, H_ = 12, D_ = 64, T_ = 10;
constexpr int N_ = B_ * S_;        // 8192
constexpr int NE_ = N_ * E_;       // 6291456
constexpr int WE_ = E_ * E_;       // 589824

typedef __attribute__((ext_vector_type(8))) short bf16x8;
typedef __attribute__((ext_vector_type(4))) float f32x4;

#define MFMA16(a,b,c) __builtin_amdgcn_mfma_f32_16x16x32_bf16(a,b,c,0,0,0)

__device__ __forceinline__ float sigm(float z){ return 1.f/(1.f+__expf(-z)); }
__device__ __forceinline__ unsigned short f2bf(float f){
    unsigned int u = __float_as_uint(f);
    u += 0x7FFFu + ((u>>16)&1u);           // RN-even
    return (unsigned short)(u>>16);
}
__device__ __forceinline__ float bf2f(unsigned short h){
    return __uint_as_float(((unsigned int)h)<<16);
}
__device__ __forceinline__ void gl16(const void* g, void* l){
    __builtin_amdgcn_global_load_lds((const __attribute__((address_space(1))) unsigned int*)g,
                                     (__attribute__((address_space(3))) unsigned int*)l, 16, 0, 0);
}

// ---------------------------------------------------------------------------
// encode: enc[t][n][e] = bf16(sigmoid(100*clip(x,0,1) - 10t)), 8 elems/thread
__global__ __launch_bounds__(256) void encode_k(const float* __restrict__ x,
                                                unsigned short* __restrict__ enc){
    const int i = blockIdx.x*256 + threadIdx.x;
    const float4 a = ((const float4*)x)[2*i];
    const float4 b = ((const float4*)x)[2*i+1];
    float p[8] = {a.x,a.y,a.z,a.w,b.x,b.y,b.z,b.w};
#pragma unroll
    for (int e=0;e<8;++e) p[e] = 100.f*fminf(fmaxf(p[e],0.f),1.f);
#pragma unroll
    for (int t=0;t<T_;++t){
        unsigned int w[4];
#pragma unroll
        for (int e=0;e<4;++e){
            unsigned short u0 = f2bf(sigm(p[2*e]   - 10.f*(float)t));
            unsigned short u1 = f2bf(sigm(p[2*e+1] - 10.f*(float)t));
            w[e] = (unsigned int)u0 | ((unsigned int)u1<<16);
        }
        ((uint4*)(enc + (long)t*NE_))[i] = make_uint4(w[0],w[1],w[2],w[3]);
    }
}

// ---------------------------------------------------------------------------
// split weights into hi/lo bf16: whi[z], wlo[z], z in {q,k,v,o}
__global__ __launch_bounds__(256) void wsplit_k(const float* __restrict__ Wq, const float* __restrict__ Wk,
        const float* __restrict__ Wv, const float* __restrict__ Wo,
        unsigned short* __restrict__ whi, unsigned short* __restrict__ wlo){
    int gi = blockIdx.x*256 + threadIdx.x;
    int z = gi / (WE_/8);
    int r = gi % (WE_/8);
    const float* W = z==0?Wq : z==1?Wk : z==2?Wv : Wo;
    const float4 a = ((const float4*)W)[2*r];
    const float4 b = ((const float4*)W)[2*r+1];
    float f[8]={a.x,a.y,a.z,a.w,b.x,b.y,b.z,b.w};
    unsigned int h[4], l[4];
#pragma unroll
    for (int e=0;e<4;++e){
        unsigned short h0=f2bf(f[2*e]),   l0=f2bf(f[2*e]  -bf2f(h0));
        unsigned short h1=f2bf(f[2*e+1]), l1=f2bf(f[2*e+1]-bf2f(h1));
        h[e] = (unsigned)h0 | ((unsigned)h1<<16);
        l[e] = (unsigned)l0 | ((unsigned)l1<<16);
    }
    ((uint4*)(whi + (long)z*WE_))[r] = make_uint4(h[0],h[1],h[2],h[3]);
    ((uint4*)(wlo + (long)z*WE_))[r] = make_uint4(l[0],l[1],l[2],l[3]);
}

// ---------------------------------------------------------------------------
// fused QKV GEMM (MFMA, W plain bf16) + in-register LIF over 10 timesteps.
// r12 CONFIG EXACTLY (measured 415us, VGPR 84, occupancy 32%): tile 128x64,
// 4 waves (2x2), single-buffered 24KB LDS, plain __syncthreads, natural grid.
// fp32 outputs — the hi/lo split epilogue (r13) cost VGPR 84->92 and 35%.
__global__ __launch_bounds__(256,2) void qkv_k(const unsigned short* __restrict__ enc,
        const unsigned short* __restrict__ whi,
        const float* __restrict__ bq, const float* __restrict__ bk, const float* __restrict__ bv,
        float* __restrict__ Qf, float* __restrict__ Kf, float* __restrict__ Vf){
    const int z = blockIdx.z;
    const unsigned short* Wh = whi + (long)z*WE_;
    const float* bias = z==0?bq : z==1?bk : bv;
    float* Out = z==0?Qf : z==1?Kf : Vf;
    const int row0 = blockIdx.x*128, col0 = blockIdx.y*64;

    __shared__ unsigned short Ab[128*64];   // 16KB
    __shared__ unsigned short Bh[64*64];    // 8KB

    const int tid = threadIdx.x, lane = tid&63, wid = tid>>6;
    const int l15 = lane&15, l4 = lane>>4, l7 = lane&7;
    const int wr = wid>>1, wc = wid&1;

    int aSrc[4], bSrc[2];
#pragma unroll
    for (int s=0;s<4;++s){
        int idx = (wid + s*4)*64 + lane;      // [0,1024)
        int row = idx>>3, ch = idx&7;
        aSrc[s] = (row0+row)*E_ + ((ch ^ (row&7))<<3);
    }
#pragma unroll
    for (int s=0;s<2;++s){
        int idx = (wid + s*4)*64 + lane;      // [0,512)
        int row = idx>>3, ch = idx&7;
        bSrc[s] = (col0+row)*E_ + ((ch ^ (row&7))<<3);
    }

    const int aBase = (wr*64 + l15)*128;
    const int bBase = (wc*32 + l15)*128;
    const int sw[2] = { ((l4^l7)<<4), ((((4+l4))^l7)<<4) };

    f32x4 acc[4][2];
    float vm[4][2][4] = {};     // membrane potential (registers across t)
    float qa[4][2][4] = {};     // spike accumulator
    float bn[2];
#pragma unroll
    for (int n=0;n<2;++n) bn[n] = bias[col0 + wc*32 + n*16 + l15];
    const f32x4 zero4 = {0.f,0.f,0.f,0.f};

    for (int t=0;t<T_;++t){
        const long tb = (long)t*NE_;
#pragma unroll
        for (int m=0;m<4;++m)
#pragma unroll
            for (int n=0;n<2;++n) acc[m][n] = zero4;
        for (int kt=0;kt<12;++kt){
            const int k0 = kt*64;
            __syncthreads();
#pragma unroll
            for (int s=0;s<4;++s)
                gl16(enc + tb + aSrc[s] + k0, &Ab[(wid+s*4)*512]);
#pragma unroll
            for (int s=0;s<2;++s)
                gl16(Wh + bSrc[s] + k0, &Bh[(wid+s*4)*512]);
            __syncthreads();
#pragma unroll
            for (int kk=0;kk<2;++kk){
                bf16x8 af[4], fbh[2];
#pragma unroll
                for (int m=0;m<4;++m)
                    af[m] = *(const bf16x8*)((const char*)Ab + aBase + m*2048 + sw[kk]);
#pragma unroll
                for (int n=0;n<2;++n)
                    fbh[n] = *(const bf16x8*)((const char*)Bh + bBase + n*2048 + sw[kk]);
#pragma unroll
                for (int m=0;m<4;++m)
#pragma unroll
                    for (int n=0;n<2;++n)
                        acc[m][n] = MFMA16(af[m], fbh[n], acc[m][n]);
            }
        }
        // LIF update, registers only (no barrier needed)
#pragma unroll
        for (int m=0;m<4;++m)
#pragma unroll
            for (int n=0;n<2;++n)
#pragma unroll
                for (int j=0;j<4;++j){
                    float I = acc[m][n][j] + bn[n];
                    float v = (vm[m][n][j] + I)*0.5f;
                    float s = sigm(10.f*v - 10.f);
                    vm[m][n][j] = v*(1.f - s);
                    qa[m][n][j] += s;
                }
    }
#pragma unroll
    for (int m=0;m<4;++m)
#pragma unroll
        for (int n=0;n<2;++n)
#pragma unroll
            for (int j=0;j<4;++j){
                int row = row0 + wr*64 + m*16 + l4*4 + j;
                int col = col0 + wc*32 + n*16 + l15;
                Out[(long)row*E_ + col] = qa[m][n][j];
            }
}

// ---------------------------------------------------------------------------
// memory-bound re-pack: Q/K fp32 -> hi/lo bf16, linear, 8 elems/thread
__global__ __launch_bounds__(256) void splitqk_k(const float* __restrict__ Qf, const float* __restrict__ Kf,
        unsigned short* __restrict__ Qh, unsigned short* __restrict__ Ql,
        unsigned short* __restrict__ Kh, unsigned short* __restrict__ Kl){
    const long gi = (long)blockIdx.x*256 + threadIdx.x;
    const float* src = blockIdx.y==0 ? Qf : Kf;
    unsigned short* oh = blockIdx.y==0 ? Qh : Kh;
    unsigned short* ol = blockIdx.y==0 ? Ql : Kl;
    const float4 a = ((const float4*)src)[2*gi];
    const float4 b = ((const float4*)src)[2*gi+1];
    float f[8]={a.x,a.y,a.z,a.w,b.x,b.y,b.z,b.w};
    unsigned int hw[4], lw[4];
#pragma unroll
    for (int e=0;e<4;++e){
        unsigned short h0=f2bf(f[2*e]),   l0=f2bf(f[2*e]  -bf2f(h0));
        unsigned short h1=f2bf(f[2*e+1]), l1=f2bf(f[2*e+1]-bf2f(h1));
        hw[e] = (unsigned)h0 | ((unsigned)h1<<16);
        lw[e] = (unsigned)l0 | ((unsigned)l1<<16);
    }
    ((uint4*)oh)[gi] = make_uint4(hw[0],hw[1],hw[2],hw[3]);
    ((uint4*)ol)[gi] = make_uint4(lw[0],lw[1],lw[2],lw[3]);
}

// ---------------------------------------------------------------------------
// V transpose + split: Vf [b][key][h*64+d] fp32 -> Vt[(b*12+h)][d][key] bf16
// hi/lo. One block per (ktile, h, b): 64 keys x 64 d via LDS transpose.
__global__ __launch_bounds__(256) void vtrans_k(const float* __restrict__ Vf,
        unsigned short* __restrict__ Vth, unsigned short* __restrict__ Vtl){
    __shared__ unsigned short lh[64][68], ll[64][68];
    const int tid = threadIdx.x;
    const long base = ((long)blockIdx.z*S_ + blockIdx.x*64)*E_ + blockIdx.y*64;

    {   // load 64x64 fp32 tile, convert, store [key][d] to LDS
        const int key = tid>>2, dq = tid&3;
        const float* p = Vf + base + (long)key*E_ + dq*16;
        float4 v0=((const float4*)p)[0], v1=((const float4*)p)[1];
        float4 v2=((const float4*)p)[2], v3=((const float4*)p)[3];
        float f[16]={v0.x,v0.y,v0.z,v0.w,v1.x,v1.y,v1.z,v1.w,
                     v2.x,v2.y,v2.z,v2.w,v3.x,v3.y,v3.z,v3.w};
#pragma unroll
        for (int i=0;i<8;++i){
            unsigned short h0=f2bf(f[2*i]),   l0=f2bf(f[2*i]  -bf2f(h0));
            unsigned short h1=f2bf(f[2*i+1]), l1=f2bf(f[2*i+1]-bf2f(h1));
            *(unsigned int*)&lh[key][dq*16+2*i] = (unsigned)h0 | ((unsigned)h1<<16);
            *(unsigned int*)&ll[key][dq*16+2*i] = (unsigned)l0 | ((unsigned)l1<<16);
        }
    }
    __syncthreads();
    {   // read transposed [d][key], write coalesced
        const int d = tid>>2, kq = tid&3;
        unsigned int hw[8], lw[8];
#pragma unroll
        for (int i=0;i<8;++i){
            unsigned short h0 = lh[kq*16+2*i][d],   h1 = lh[kq*16+2*i+1][d];
            unsigned short l0 = ll[kq*16+2*i][d],   l1 = ll[kq*16+2*i+1][d];
            hw[i] = (unsigned)h0 | ((unsigned)h1<<16);
            lw[i] = (unsigned)l0 | ((unsigned)l1<<16);
        }
        long o = ((long)(blockIdx.z*12 + blockIdx.y))*65536 + (long)d*1024
               + blockIdx.x*64 + kq*16;
        ((uint4*)&Vth[o])[0] = make_uint4(hw[0],hw[1],hw[2],hw[3]);
        ((uint4*)&Vth[o])[1] = make_uint4(hw[4],hw[5],hw[6],hw[7]);
        ((uint4*)&Vtl[o])[0] = make_uint4(lw[0],lw[1],lw[2],lw[3]);
        ((uint4*)&Vtl[o])[1] = make_uint4(lw[4],lw[5],lw[6],lw[7]);
    }
}

// ---------------------------------------------------------------------------
// flash attention, hi/lo-split bf16 MFMA. Per block: 64 q-rows, one (b,h).
// All staging is pure global_load_lds (inputs pre-split/pre-transposed;
// source pre-inverse-swizzled, LDS contents bit-identical to r12 path).
__global__ __launch_bounds__(256,2) void attn_k2(
        const unsigned short* __restrict__ Qh_g, const unsigned short* __restrict__ Ql_g,
        const unsigned short* __restrict__ Kh_g, const unsigned short* __restrict__ Kl_g,
        const unsigned short* __restrict__ Vth_g, const unsigned short* __restrict__ Vtl_g,
        unsigned short* __restrict__ atth, unsigned short* __restrict__ attl){
    const int q0 = blockIdx.x*64;
    const int h  = blockIdx.y;
    const int b  = blockIdx.z;
    const long base = ((long)b*S_)*E_ + h*64;
    const long vtb  = (long)(b*12 + h) * 65536;

    __shared__ char smem[65536];
    unsigned short* QhL = (unsigned short*)(smem);
    unsigned short* QlL = (unsigned short*)(smem + 8192);
    unsigned short* KhL = (unsigned short*)(smem + 16384);
    unsigned short* KlL = (unsigned short*)(smem + 24576);
    unsigned short* VhL = (unsigned short*)(smem + 32768);  // [d][key] transposed
    unsigned short* VlL = (unsigned short*)(smem + 40960);
    unsigned short* Ph = (unsigned short*)(smem + 49152);   // [q][key]
    unsigned short* Pl = (unsigned short*)(smem + 57344);
    float* OT = (float*)(smem + 16384);                     // [64][68] reuse K/V region

    const int tid = threadIdx.x, lane = tid&63, wid = tid>>6;
    const int l15 = lane&15, l4 = lane>>4, l7 = lane&7;
    const int qrow = wid*16 + l15;

    // staging source offsets (element units), LDS dest linear
    int sOff[2], vOff[2];
#pragma unroll
    for (int s=0;s<2;++s){
        int idx = (wid + s*4)*64 + lane;      // [0,512)
        int r = idx>>3, c = idx&7;
        sOff[s] = r*E_ + ((c ^ (r&7))<<3);    // Q/K rows in [N][E]
        vOff[s] = (r<<10) + ((c ^ (r&7))<<3); // Vt rows (d) stride 1024
    }

    // stage Q (hi+lo) once
#pragma unroll
    for (int s=0;s<2;++s){
        gl16(Qh_g + base + (long)q0*E_ + sOff[s], &QhL[(wid+s*4)*512]);
        gl16(Ql_g + base + (long)q0*E_ + sOff[s], &QlL[(wid+s*4)*512]);
    }
    __syncthreads();
    bf16x8 qfh[2], qfl[2];
#pragma unroll
    for (int kk=0;kk<2;++kk){
        int off = qrow*128 + ((((kk<<2)+l4) ^ l7)<<4);
        qfh[kk] = *(const bf16x8*)((const char*)QhL + off);
        qfl[kk] = *(const bf16x8*)((const char*)QlL + off);
    }

    float mrun = -1e30f, lrun = 0.f;
    f32x4 ot[4];
    const f32x4 zero4 = {0.f,0.f,0.f,0.f};
#pragma unroll
    for (int m=0;m<4;++m) ot[m] = zero4;

    for (int kt=0;kt<16;++kt){
        const int k0 = kt*64;
        __syncthreads();   // previous tile's LDS reads done
#pragma unroll
        for (int s=0;s<2;++s){
            gl16(Kh_g + base + (long)k0*E_ + sOff[s], &KhL[(wid+s*4)*512]);
            gl16(Kl_g + base + (long)k0*E_ + sOff[s], &KlL[(wid+s*4)*512]);
            gl16(Vth_g + vtb + k0 + vOff[s], &VhL[(wid+s*4)*512]);
            gl16(Vtl_g + vtb + k0 + vOff[s], &VlL[(wid+s*4)*512]);
        }
        __syncthreads();
        // S^T = K * Q^T  (3 hi/lo products)
        f32x4 st[4];
#pragma unroll
        for (int m=0;m<4;++m) st[m] = zero4;
#pragma unroll
        for (int kk=0;kk<2;++kk){
            int swo = ((((kk<<2)+l4) ^ l7)<<4);
            bf16x8 kh[4], kl2[4];
#pragma unroll
            for (int m=0;m<4;++m){
                int off = (m*16+l15)*128 + swo;
                kh[m]  = *(const bf16x8*)((const char*)KhL + off);
                kl2[m] = *(const bf16x8*)((const char*)KlL + off);
            }
#pragma unroll
            for (int m=0;m<4;++m){
                st[m] = MFMA16(kh[m],  qfh[kk], st[m]);
                st[m] = MFMA16(kh[m],  qfl[kk], st[m]);
                st[m] = MFMA16(kl2[m], qfh[kk], st[m]);
            }
        }
        // online softmax (lane's q = qrow; 4 lanes share a q via xor16/32)
        float pmax = -1e30f;
#pragma unroll
        for (int m=0;m<4;++m)
#pragma unroll
            for (int j=0;j<4;++j){ st[m][j] *= 0.125f; pmax = fmaxf(pmax, st[m][j]); }
        pmax = fmaxf(pmax, __shfl_xor(pmax,16));
        pmax = fmaxf(pmax, __shfl_xor(pmax,32));
        float mnew = fmaxf(mrun, pmax);
        float alpha = __expf(mrun - mnew);
        float p[16]; float psum = 0.f;
#pragma unroll
        for (int m=0;m<4;++m)
#pragma unroll
            for (int j=0;j<4;++j){ float e = __expf(st[m][j]-mnew); p[m*4+j]=e; psum+=e; }
        psum += __shfl_xor(psum,16);
        psum += __shfl_xor(psum,32);
        lrun = lrun*alpha + psum;
        mrun = mnew;
#pragma unroll
        for (int m=0;m<4;++m)
#pragma unroll
            for (int j=0;j<4;++j) ot[m][j] *= alpha;
        // write P^T split (wave-private rows, packed pairs)
#pragma unroll
        for (int m=0;m<4;++m)
#pragma unroll
            for (int jp=0;jp<2;++jp){
                float fx = p[m*4+jp*2], fy = p[m*4+jp*2+1];
                unsigned short hx=f2bf(fx), hy=f2bf(fy);
                unsigned short lx=f2bf(fx-bf2f(hx)), ly=f2bf(fy-bf2f(hy));
                int key = m*16 + l4*4 + jp*2;
                int byte = qrow*128 + ((key<<1) ^ (l7<<4));
                *(unsigned int*)((char*)Ph + byte) = (unsigned)hx | ((unsigned)hy<<16);
                *(unsigned int*)((char*)Pl + byte) = (unsigned)lx | ((unsigned)ly<<16);
            }
        // O^T += V^T * P^T (3 hi/lo products)
#pragma unroll
        for (int kk=0;kk<2;++kk){
            int swo = ((((kk<<2)+l4) ^ l7)<<4);
            bf16x8 pfh = *(const bf16x8*)((const char*)Ph + qrow*128 + swo);
            bf16x8 pfl = *(const bf16x8*)((const char*)Pl + qrow*128 + swo);
#pragma unroll
            for (int m=0;m<4;++m){
                int off = (m*16+l15)*128 + swo;
                bf16x8 vvh = *(const bf16x8*)((const char*)VhL + off);
                bf16x8 vvl = *(const bf16x8*)((const char*)VlL + off);
                ot[m] = MFMA16(vvh, pfh, ot[m]);
                ot[m] = MFMA16(vvh, pfl, ot[m]);
                ot[m] = MFMA16(vvl, pfh, ot[m]);
            }
        }
    }
    __syncthreads();
    // normalize + transpose via LDS, write att split bf16
    float inv = 1.f/lrun;
#pragma unroll
    for (int m=0;m<4;++m)
#pragma unroll
        for (int j=0;j<4;++j){
            int d = m*16 + l4*4 + j;
            OT[qrow*68 + d] = ot[m][j]*inv;
        }
    __syncthreads();
    {
        int q = tid>>2, d0 = (tid&3)*16;
        const float* rp = OT + q*68 + d0;
        float4 f0=((const float4*)rp)[0], f1=((const float4*)rp)[1];
        float4 f2=((const float4*)rp)[2], f3=((const float4*)rp)[3];
        float f[16]={f0.x,f0.y,f0.z,f0.w,f1.x,f1.y,f1.z,f1.w,f2.x,f2.y,f2.z,f2.w,f3.x,f3.y,f3.z,f3.w};
        bf16x8 vh[2], vl[2];
#pragma unroll
        for (int g=0;g<2;++g)
#pragma unroll
            for (int e=0;e<8;++e){
                unsigned short hh = f2bf(f[g*8+e]);
                vh[g][e] = (short)hh;
                vl[g][e] = (short)f2bf(f[g*8+e]-bf2f(hh));
            }
        long o = base + (long)(q0+q)*E_ + d0;
        *(bf16x8*)(atth + o)     = vh[0];
        *(bf16x8*)(atth + o + 8) = vh[1];
        *(bf16x8*)(attl + o)     = vl[0];
        *(bf16x8*)(attl + o + 8) = vl[1];
    }
}

// ---------------------------------------------------------------------------
// output projection GEMM: (att_hi + att_lo) x Wo_hi (2 products) + spike
__global__ __launch_bounds__(256,2) void out_k(const unsigned short* __restrict__ Ah_g,
        const unsigned short* __restrict__ Al_g,
        const unsigned short* __restrict__ Wh,
        const float* __restrict__ bias, float* __restrict__ out){
    const int row0 = blockIdx.x*128, col0 = blockIdx.y*64;
    __shared__ unsigned short Ah[128*64], Al[128*64];
    __shared__ unsigned short Bh2[64*64];

    const int tid = threadIdx.x, lane = tid&63, wid = tid>>6;
    const int l15 = lane&15, l4 = lane>>4, l7 = lane&7;
    const int wr = wid>>1, wc = wid&1;

    int aSrc[4], bSrc[2];
#pragma unroll
    for (int s=0;s<4;++s){
        int idx = (wid + s*4)*64 + lane;
        int row = idx>>3, ch = idx&7;
        aSrc[s] = (row0+row)*E_ + ((ch ^ (row&7))<<3);
    }
#pragma unroll
    for (int s=0;s<2;++s){
        int idx = (wid + s*4)*64 + lane;
        int row = idx>>3, ch = idx&7;
        bSrc[s] = (col0+row)*E_ + ((ch ^ (row&7))<<3);
    }
    const int aBase = (wr*64 + l15)*128;
    const int bBase = (wc*32 + l15)*128;
    const int sw[2] = { ((l4^l7)<<4), ((((4+l4))^l7)<<4) };

    f32x4 acc[4][2];
    const f32x4 zero4 = {0.f,0.f,0.f,0.f};
#pragma unroll
    for (int m=0;m<4;++m)
#pragma unroll
        for (int n=0;n<2;++n) acc[m][n] = zero4;

    for (int kt=0;kt<12;++kt){
        const int k0 = kt*64;
        __syncthreads();
#pragma unroll
        for (int s=0;s<4;++s){
            gl16(Ah_g + aSrc[s] + k0, &Ah[(wid+s*4)*512]);
            gl16(Al_g + aSrc[s] + k0, &Al[(wid+s*4)*512]);
        }
#pragma unroll
        for (int s=0;s<2;++s)
            gl16(Wh + bSrc[s] + k0, &Bh2[(wid+s*4)*512]);
        __syncthreads();
#pragma unroll
        for (int kk=0;kk<2;++kk){
            bf16x8 ah[4], al[4], fbh[2];
#pragma unroll
            for (int m=0;m<4;++m){
                ah[m] = *(const bf16x8*)((const char*)Ah + aBase + m*2048 + sw[kk]);
                al[m] = *(const bf16x8*)((const char*)Al + aBase + m*2048 + sw[kk]);
            }
#pragma unroll
            for (int n=0;n<2;++n)
                fbh[n] = *(const bf16x8*)((const char*)Bh2 + bBase + n*2048 + sw[kk]);
#pragma unroll
            for (int m=0;m<4;++m)
#pragma unroll
                for (int n=0;n<2;++n){
                    acc[m][n] = MFMA16(ah[m], fbh[n], acc[m][n]);
                    acc[m][n] = MFMA16(al[m], fbh[n], acc[m][n]);
                }
        }
    }
#pragma unroll
    for (int m=0;m<4;++m)
#pragma unroll
        for (int n=0;n<2;++n){
            float bn = bias[col0 + wc*32 + n*16 + l15];
#pragma unroll
            for (int j=0;j<4;++j){
                int row = row0 + wr*64 + m*16 + l4*4 + j;
                int col = col0 + wc*32 + n*16 + l15;
                float I = acc[m][n][j] + bn;
                out[(long)row*E_ + col] = sigm(5.f*I - 10.f);   // lif_step(0, I) spike
            }
        }
}

// ---------------------------------------------------------------------------
extern "C" void kernel_launch(void* const* d_in, const int* in_sizes, int n_in,
                              void* d_out, int out_size, void* d_ws, size_t ws_size,
                              hipStream_t stream){
    const float* x  = (const float*)d_in[0];
    const float* Wq = (const float*)d_in[1];
    const float* bq = (const float*)d_in[2];
    const float* Wk = (const float*)d_in[3];
    const float* bk = (const float*)d_in[4];
    const float* Wv = (const float*)d_in[5];
    const float* bv = (const float*)d_in[6];
    const float* Wo = (const float*)d_in[7];
    const float* bo = (const float*)d_in[8];
    float* out = (float*)d_out;

    // ws layout (210763776 B):
    //  [0, 125829120)         enc bf16 [10][N][E]  (dead after qkv_k; region reused:
    //      [0, 25165824)          atth/attl
    //      [25165824, 100663296)  Qh/Ql/Kh/Kl [N][E] + Vth/Vtl [B*H][64][1024] bf16)
    //  [125829120, 135266304) whi/wlo bf16 [4][E*E]
    //  [135266304, 210763776) Qf/Kf/Vf fp32 [N][E]
    char* ws = (char*)d_ws;
    unsigned short* enc  = (unsigned short*)ws;
    unsigned short* atth = (unsigned short*)ws;
    unsigned short* attl = (unsigned short*)(ws + (long)NE_*2);
    unsigned short* Qh_g  = (unsigned short*)(ws + 25165824L);
    unsigned short* Ql_g  = Qh_g + NE_;
    unsigned short* Kh_g  = Ql_g + NE_;
    unsigned short* Kl_g  = Kh_g + NE_;
    unsigned short* Vth_g = Kl_g + NE_;
    unsigned short* Vtl_g = Vth_g + NE_;
    unsigned short* whi  = (unsigned short*)(ws + 125829120L);
    unsigned short* wlo  = whi + 4L*WE_;
    float* Qf = (float*)(ws + 135266304L);
    float* Kf = Qf + NE_;
    float* Vf = Kf + NE_;

    wsplit_k<<<dim3(4*(WE_/8)/256), 256, 0, stream>>>(Wq,Wk,Wv,Wo,whi,wlo);
    encode_k<<<dim3(NE_/8/256), 256, 0, stream>>>(x,enc);
    qkv_k<<<dim3(64,12,3), 256, 0, stream>>>(enc,whi,bq,bk,bv,Qf,Kf,Vf);
    splitqk_k<<<dim3(NE_/8/256, 2), 256, 0, stream>>>(Qf,Kf,Qh_g,Ql_g,Kh_g,Kl_g);
    vtrans_k<<<dim3(16,12,8), 256, 0, stream>>>(Vf,Vth_g,Vtl_g);
    attn_k2<<<dim3(16,12,8), 256, 0, stream>>>(Qh_g,Ql_g,Kh_g,Kl_g,Vth_g,Vtl_g,
                                               atth,attl);
    out_k<<<dim3(64,12), 256, 0, stream>>>(atth,attl,whi+3L*WE_,bo,out);
}